// Round 19
// baseline (273.041 us; speedup 1.0000x reference)
//
#include <hip/hip_runtime.h>
#include <hip/hip_bf16.h>

typedef __attribute__((ext_vector_type(4))) float f32x4;
typedef __attribute__((ext_vector_type(8))) short s16x8;
typedef __attribute__((ext_vector_type(4))) short s16x4;
typedef __attribute__((ext_vector_type(4))) unsigned int u32x4;

#define MFMA16(A, B, C) __builtin_amdgcn_mfma_f32_16x16x32_bf16((A), (B), (C), 0, 0, 0)

#define GLDS16(gsrc, ldst) __builtin_amdgcn_global_load_lds(                   \
    (const __attribute__((address_space(1))) void*)(gsrc),                    \
    (__attribute__((address_space(3))) void*)(ldst), 16, 0, 0)

__device__ __forceinline__ ushort f2bf(float f) {
    __hip_bfloat16 h = __float2bfloat16(f);
    return *reinterpret_cast<ushort*>(&h);
}

// p = exp(gelu_tanh(x)) : y = 0.79788456x(1+0.044715x^2); g = x*sigmoid(2y)
// e2 = 2^(x*(c1*x^2+c0)) = e^{-2y}; g = x/(1+e2); p = e^g.
__device__ __forceinline__ float exp_gelu(float x) {
    float u = x * x;
    float m = fmaf(-0.1029439065f, u, -2.3022154392f);   // -2*log2(e)*0.79788456*(1, 0.044715)
    float e2 = __builtin_amdgcn_exp2f(x * m);
    float g = x * __builtin_amdgcn_rcpf(1.0f + e2);
    return __expf(g);
}

// ---------------- fused stage-0 prep ----------------
// [0,9600) cvt | [9600,9856) twT W_gen | [9856,10880) twT W_val
// [10880,11904) twT W_out | [11904,12704) wbbT transpose | [12704,13216) pad9
// wbbT layout: [h][k>>2][q][k&3] packed {bf16 wb, bf16 bias} u32 -> one 16B
// load covers k..k+3 for a given q.
__global__ __launch_bounds__(256) void k_prep(const float* __restrict__ qf,
                                              ushort* __restrict__ qf_bf,
                                              const float* __restrict__ W_gen,
                                              const float* __restrict__ W_val,
                                              const float* __restrict__ W_out,
                                              const float* __restrict__ wb,
                                              const float* __restrict__ bias,
                                              ushort* __restrict__ WgvT,
                                              ushort* __restrict__ WoT,
                                              unsigned int* __restrict__ wbbT,
                                              ushort* __restrict__ Vt) {
    __shared__ float tile[32][33];
    __shared__ float tb[32][33];
    int blk = blockIdx.x;
    int tx = threadIdx.x & 31, ty = threadIdx.x >> 5;   // 32 x 8
    if (blk < 9600) {                       // qf f32 -> bf16
        int i = (blk * 256 + threadIdx.x) * 4;
        float4 v = *(const float4*)(qf + i);
        ushort4 o;
        o.x = f2bf(v.x); o.y = f2bf(v.y); o.z = f2bf(v.z); o.w = f2bf(v.w);
        *(ushort4*)(qf_bf + i) = o;
        return;
    }
    blk -= 9600;
    if (blk < 2304) {                       // weight transposes
        const float* w; ushort* wt; int K, N, kx, ny;
        if (blk < 256)       { w = W_gen; wt = WgvT;             K = 512;  N = 512;
                               kx = blk & 15;          ny = blk >> 4; }
        else if (blk < 1280) { w = W_val; wt = WgvT + 512 * 512; K = 512;  N = 2048;
                               int b2 = blk - 256;  kx = b2 & 15; ny = b2 >> 4; }
        else                 { w = W_out; wt = WoT;              K = 2048; N = 512;
                               int b2 = blk - 1280; kx = b2 & 63; ny = b2 >> 6; }
        int k0 = kx * 32, n0 = ny * 32;
        #pragma unroll
        for (int i = ty; i < 32; i += 8)
            tile[i][tx] = w[(size_t)(k0 + i) * N + n0 + tx];
        __syncthreads();
        #pragma unroll
        for (int i = ty; i < 32; i += 8)
            wt[(size_t)(n0 + i) * K + k0 + tx] = f2bf(tile[tx][i]);
        return;
    }
    blk -= 2304;
    if (blk < 800) {                        // wbbT[h][k>>2][q][k&3]
        int h = blk / 100, rem = blk - h * 100;
        int kx = rem / 10, qx = rem - kx * 10;
        int k0 = kx * 32, q0 = qx * 32;
        #pragma unroll
        for (int i = ty; i < 32; i += 8)
            if (q0 + i < 300 && k0 + tx < 300) {
                size_t si = ((size_t)h * 300 + q0 + i) * 300 + k0 + tx;
                tile[i][tx] = wb[si];
                tb[i][tx]   = bias[si];
            }
        __syncthreads();
        #pragma unroll
        for (int i = ty; i < 32; i += 8)
            if (k0 + i < 300 && q0 + tx < 300) {
                int k = k0 + i;
                unsigned int pk = (unsigned int)f2bf(tile[tx][i])
                                | ((unsigned int)f2bf(tb[tx][i]) << 16);
                wbbT[(((size_t)h * 75 + (k >> 2)) * 300 + (q0 + tx)) * 4 + (k & 3)] = pk;
            }
        return;
    }
    blk -= 800;                             // zero chunk-9 pad (keys 300..303)
    int tid = blk * 256 + threadIdx.x;      // < 131072
    int bh = tid >> 8, v = tid & 255;
    *(s16x4*)(Vt + (size_t)bh * 77824 + 73728 + v * 16 + 12) = (s16x4){0, 0, 0, 0};
}

// ---------------- 256x256 GEMM (r11-validated structure) ----------------
// Vt layout: per (b*8+h): chunks 0..8 [256v][32k] + chunk9 [256v][16k]
// (77824 ushorts per bh).
template <int OUT>
__global__ __launch_bounds__(512, 2) void k_gemm256(const ushort* __restrict__ A,
                                                    const ushort* __restrict__ BT,
                                                    const float* __restrict__ b1,
                                                    const float* __restrict__ b2,
                                                    void* __restrict__ o1,
                                                    void* __restrict__ o2,
                                                    int K, int GY) {
    __shared__ __align__(16) ushort As[2][256 * 64];   // 2 x 32 KiB
    __shared__ __align__(16) ushort Bs[2][256 * 64];   // 2 x 32 KiB
    int id = blockIdx.x;
    int xcd = id & 7, s = id >> 3;
    int mxl = s / GY, ny = s - mxl * GY;
    int mx = xcd * 10 + mxl;
    if (mx >= 75) return;
    int m0 = mx * 256, n0g = ny * 256;

    int t = threadIdx.x, l = t & 63, w = t >> 6;
    int wr = w >> 2, wc = w & 3;            // 2 x 4 wave grid
    int lr = l & 15, lg = l >> 4;

    int rsrc[4], ksrc[4];
    #pragma unroll
    for (int c8 = 0; c8 < 4; ++c8) {
        int o = (c8 * 512 + t) * 16;
        int op = o ^ (((o >> 7) & 7) << 4);
        rsrc[c8] = op >> 7;                 // 0..255
        ksrc[c8] = (op & 127) >> 1;         // 0..63 (multiple of 8)
    }

    auto stage = [&](int kt, int buf) {
        int k0 = kt * 64;
        ushort* AsB = &As[buf][0];
        ushort* BsB = &Bs[buf][0];
        #pragma unroll
        for (int c8 = 0; c8 < 4; ++c8) {
            int dst = (c8 * 512 + w * 64) * 8;      // wave-uniform, ushorts
            GLDS16(A  + (size_t)(m0 + rsrc[c8]) * K + k0 + ksrc[c8], AsB + dst);
            GLDS16(BT + (size_t)(n0g + rsrc[c8]) * K + k0 + ksrc[c8], BsB + dst);
        }
    };

    f32x4 acc[8][4];
    #pragma unroll
    for (int i = 0; i < 8; ++i)
        #pragma unroll
        for (int j = 0; j < 4; ++j)
            acc[i][j] = (f32x4){0.f, 0.f, 0.f, 0.f};

    int NT = K >> 6;
    stage(0, 0);
    stage(1, 1);

    for (int kt = 0; kt < NT; ++kt) {
        if (kt + 1 < NT) asm volatile("s_waitcnt vmcnt(8)" ::: "memory");
        else             asm volatile("s_waitcnt vmcnt(0)" ::: "memory");
        __builtin_amdgcn_s_barrier();       // tile kt fully in LDS (all waves)

        int cur = kt & 1;
        const char* Ab = (const char*)&As[cur][0];
        const char* Bb = (const char*)&Bs[cur][0];
        #pragma unroll
        for (int ks = 0; ks < 2; ++ks) {
            int kb = (ks * 64 + lg * 16) ^ ((lr & 7) << 4);
            s16x8 af[8], bfv[4];
            #pragma unroll
            for (int rt = 0; rt < 8; ++rt)
                af[rt] = *(const s16x8*)(Ab + (wr * 128 + rt * 16 + lr) * 128 + kb);
            #pragma unroll
            for (int ct = 0; ct < 4; ++ct)
                bfv[ct] = *(const s16x8*)(Bb + (wc * 64 + ct * 16 + lr) * 128 + kb);
            #pragma unroll
            for (int rt = 0; rt < 8; ++rt)
                #pragma unroll
                for (int ct = 0; ct < 4; ++ct)
                    acc[rt][ct] = MFMA16(af[rt], bfv[ct], acc[rt][ct]);
        }

        __builtin_amdgcn_s_barrier();       // all waves done reading buf cur
        if (kt + 2 < NT) stage(kt + 2, cur);
    }

    if (OUT == 0) {
        if (n0g < 512) {
            ushort* G = (ushort*)o1;
            #pragma unroll
            for (int rt = 0; rt < 8; ++rt)
                #pragma unroll
                for (int ct = 0; ct < 4; ++ct) {
                    int col = n0g + wc * 64 + ct * 16 + lr;
                    float bv = b1[col];
                    #pragma unroll
                    for (int rr = 0; rr < 4; ++rr) {
                        int row = m0 + wr * 128 + rt * 16 + lg * 4 + rr;
                        G[(size_t)row * 512 + col] = f2bf(acc[rt][ct][rr] + bv);
                    }
                }
        } else {
            ushort* Vt = (ushort*)o2;
            #pragma unroll
            for (int rt = 0; rt < 8; ++rt) {
                int rl0 = m0 + wr * 128 + rt * 16 + lg * 4;   // %4 == 0
                int bb = rl0 / 300, key0 = rl0 - bb * 300;    // key0 %4 == 0
                #pragma unroll
                for (int ct = 0; ct < 4; ++ct) {
                    int colv = n0g - 512 + wc * 64 + ct * 16 + lr;
                    float bv = b2[colv];
                    int hh = colv >> 8, v = colv & 255;
                    s16x4 pw;
                    #pragma unroll
                    for (int rr = 0; rr < 4; ++rr)
                        pw[rr] = (short)f2bf(acc[rt][ct][rr] + bv);
                    size_t bhb = (size_t)(bb * 8 + hh) * 77824;
                    size_t addr = (key0 < 288)
                        ? bhb + (size_t)(key0 >> 5) * 8192 + v * 32 + (key0 & 31)
                        : bhb + 73728 + v * 16 + (key0 - 288);
                    *(s16x4*)(Vt + addr) = pw;
                }
            }
        }
    } else {
        float* out = (float*)o1;
        #pragma unroll
        for (int rt = 0; rt < 8; ++rt)
            #pragma unroll
            for (int ct = 0; ct < 4; ++ct) {
                int col = n0g + wc * 64 + ct * 16 + lr;
                float bv = b1[col];
                #pragma unroll
                for (int rr = 0; rr < 4; ++rr) {
                    int row = m0 + wr * 128 + rt * 16 + lg * 4 + rr;
                    size_t idx = (size_t)row * 512 + col;
                    out[idx] = acc[rt][ct][rr] + bv + b2[idx];
                }
            }
    }
}

// ---------------- fused attention: 512 threads (8 waves) ----------------
// Scores: wave (wq,wk) computes 16 q-rows x its key-half; wb/bias via one
// 16B u32x4 load per kt. PV: wave w owns v in [w*32,w*32+32).
// P stride 312 (624 B/row): non-pow2 stride spreads banks naturally (no XOR);
// LDS = 39,936 + 512 = 40,448 B <= 40,960 -> 4 blocks/CU now fit the pool.
__global__ __launch_bounds__(512, 6) void k_attn(const ushort* __restrict__ qf_bf,
                                                 const ushort* __restrict__ G_bf,
                                                 const ushort* __restrict__ Vt,
                                                 const unsigned int* __restrict__ wbb,
                                                 ushort* __restrict__ O) {
    __shared__ __align__(16) ushort P[64 * 312];   // 39,936 B
    __shared__ float partial[2][64];
    int id = blockIdx.x;
    int xcd = id & 7, s = id >> 3;        // s in [0,320)
    int h = s / 40; int r2 = s - h * 40;
    int bi = r2 / 5, qt = r2 - bi * 5;
    int b = xcd * 8 + bi;

    int t = threadIdx.x, l = t & 63, w = t >> 6;
    int lr = l & 15, lg = l >> 4;
    int wq = w & 3, wk = w >> 2;

    auto p_addr = [&](int q, int k) -> ushort* {
        return (ushort*)P + q * 312 + k;
    };

    // Q fragment (B operand): col = q = lane&15
    int qr = min(qt * 64 + wq * 16 + lr, 299);
    const ushort* qp = qf_bf + ((size_t)(b * 300 + qr)) * 512 + h * 64 + lg * 8;
    s16x8 q0 = *(const s16x8*)(qp);
    s16x8 q1 = *(const s16x8*)(qp + 32);

    // wbb element base for this (h, q); group g = kt*4+lg steps by 1200 dwords
    const unsigned int* wbbq = wbb + (size_t)h * 90000 + qr * 4;

    // ---- scores^T streamed over this wave's key-half ----
    int qq = wq * 16 + lr;
    float ssum = 0.f;
    int ktlo = wk * 10, kthi = min(ktlo + 10, 18);
    const unsigned int* wp = wbbq + (size_t)(ktlo * 4 + lg) * 1200;
    const ushort* gp = G_bf + ((size_t)(b * 300) + ktlo * 16 + lr) * 512 + h * 64 + lg * 8;
    for (int kt = ktlo; kt < kthi; ++kt) {              // clamp-free main loop
        s16x8 g0 = *(const s16x8*)(gp);
        s16x8 g1 = *(const s16x8*)(gp + 32);
        f32x4 a = (f32x4){0.f, 0.f, 0.f, 0.f};
        a = MFMA16(g0, q0, a);
        a = MFMA16(g1, q1, a);
        u32x4 uv = *(const u32x4*)(wp);
        int kbase = kt * 16 + lg * 4;
        s16x4 pw;
        #pragma unroll
        for (int r = 0; r < 4; ++r) {
            unsigned int u = uv[r];
            float wv = __builtin_bit_cast(float, u << 16);
            float bv = __builtin_bit_cast(float, u & 0xffff0000u);
            float x = fmaf(a[r], wv, bv);
            float p = exp_gelu(x);
            ssum += p;
            pw[r] = (short)f2bf(p);
        }
        *(s16x4*)p_addr(qq, kbase) = pw;
        wp += 4800;                 // 4 groups x 1200 dwords
        gp += 16 * 512;             // 16 key-rows
    }
    if (wk == 1) {                                      // peeled kt = 18
        int kcl = min(288 + lr, 299);
        const ushort* gpe = G_bf + ((size_t)(b * 300 + kcl)) * 512 + h * 64 + lg * 8;
        s16x8 g0 = *(const s16x8*)(gpe);
        s16x8 g1 = *(const s16x8*)(gpe + 32);
        f32x4 a = (f32x4){0.f, 0.f, 0.f, 0.f};
        a = MFMA16(g0, q0, a);
        a = MFMA16(g1, q1, a);
        int kbase = 288 + lg * 4;
        int g4 = min(72 + lg, 74);                      // lg=3 clamped (masked)
        u32x4 uv = *(const u32x4*)(wbbq + (size_t)g4 * 1200);
        s16x4 pw;
        #pragma unroll
        for (int r = 0; r < 4; ++r) {
            unsigned int u = uv[r];
            float wv = __builtin_bit_cast(float, u << 16);
            float bv = __builtin_bit_cast(float, u & 0xffff0000u);
            float x = fmaf(a[r], wv, bv);
            float p = (lg < 3) ? exp_gelu(x) : 0.f;
            ssum += p;
            pw[r] = (short)f2bf(p);
        }
        *(s16x4*)p_addr(qq, kbase) = pw;
    }

    // per-wave partial denominator for row qq (sum over lg groups)
    ssum += __shfl_xor(ssum, 16);
    ssum += __shfl_xor(ssum, 32);
    if (lg == 0) partial[wk][qq] = ssum;

    __syncthreads();   // the ONLY barrier: P + partial visible

    // ---- PV: wave w owns v in [w*32, w*32+32) for all 64 q ----
    f32x4 acc[4][2];   // [qg][nt]
    #pragma unroll
    for (int qg = 0; qg < 4; ++qg)
        #pragma unroll
        for (int nt = 0; nt < 2; ++nt)
            acc[qg][nt] = (f32x4){0.f, 0.f, 0.f, 0.f};

    size_t bhb = (size_t)(b * 8 + h) * 77824;
    const ushort* vbase = Vt + bhb + (size_t)(w * 32) * 32 + lg * 8;
    #pragma unroll
    for (int kc = 0; kc < 9; ++kc) {
        s16x8 vb0 = *(const s16x8*)(vbase + (size_t)kc * 8192 + lr * 32);
        s16x8 vb1 = *(const s16x8*)(vbase + (size_t)kc * 8192 + (16 + lr) * 32);
        #pragma unroll
        for (int qg = 0; qg < 4; ++qg) {
            s16x8 pa = *(const s16x8*)p_addr(qg * 16 + lr, kc * 32 + lg * 8);
            acc[qg][0] = MFMA16(pa, vb0, acc[qg][0]);
            acc[qg][1] = MFMA16(pa, vb1, acc[qg][1]);
        }
    }
    {   // chunk 9: keys 288..303 (16-wide); lanes lg>=2 contribute zeros
        const ushort* c9 = Vt + bhb + 73728 + (size_t)(w * 32) * 16 + lg * 8;
        s16x8 vb0, vb1;
        if (lg < 2) {
            vb0 = *(const s16x8*)(c9 + lr * 16);
            vb1 = *(const s16x8*)(c9 + (16 + lr) * 16);
        } else {
            vb0 = (s16x8){0,0,0,0,0,0,0,0};
            vb1 = (s16x8){0,0,0,0,0,0,0,0};
        }
        #pragma unroll
        for (int qg = 0; qg < 4; ++qg) {
            s16x8 pa = (lg < 2)
                ? *(const s16x8*)p_addr(qg * 16 + lr, 288 + lg * 8)
                : (s16x8){0,0,0,0,0,0,0,0};
            acc[qg][0] = MFMA16(pa, vb0, acc[qg][0]);
            acc[qg][1] = MFMA16(pa, vb1, acc[qg][1]);
        }
    }

    // ---- normalize + store ----
    #pragma unroll
    for (int qg = 0; qg < 4; ++qg)
        #pragma unroll
        for (int r = 0; r < 4; ++r) {
            int qloc = qg * 16 + lg * 4 + r;
            int q = qt * 64 + qloc;
            if (q < 300) {
                float iv = 1.0f / (partial[0][qloc] + partial[1][qloc]);
                #pragma unroll
                for (int nt = 0; nt < 2; ++nt) {
                    int v = w * 32 + nt * 16 + lr;
                    O[((size_t)(b * 300 + q)) * 2048 + h * 256 + v] =
                        f2bf(acc[qg][nt][r] * iv);
                }
            }
        }
}

extern "C" void kernel_launch(void* const* d_in, const int* in_sizes, int n_in,
                              void* d_out, int out_size, void* d_ws, size_t ws_size,
                              hipStream_t stream) {
    const float* qf    = (const float*)d_in[0];
    const float* bias  = (const float*)d_in[1];
    const float* W_gen = (const float*)d_in[2];
    const float* b_gen = (const float*)d_in[3];
    const float* W_val = (const float*)d_in[4];
    const float* b_val = (const float*)d_in[5];
    const float* W_out = (const float*)d_in[6];
    const float* b_out = (const float*)d_in[7];
    const float* wb    = (const float*)d_in[8];
    float* out = (float*)d_out;

    char* ws = (char*)d_ws;
    ushort* qf_bf = (ushort*)(ws);                       // 19,660,800 B
    ushort* G_bf  = (ushort*)(ws + 19660800);            // 19,660,800 B
    ushort* Vt    = (ushort*)(ws + 39321600);            // 79,691,776 B (tiled)
    ushort* O_bf  = (ushort*)(ws + 119013376);           // 78,643,200 B
    ushort* WgvT  = (ushort*)(ws + 197656576);           //  2,621,440 B
    ushort* WoT   = (ushort*)(ws + 200278016);           //  2,097,152 B
    unsigned int* wbbT = (unsigned int*)(ws + 202375168);//  2,880,000 B -> 205,255,168

    // stage 0 (fused): cvt + transposes + wbbT + chunk9 pad
    k_prep<<<dim3(13216), dim3(256), 0, stream>>>(qf, qf_bf, W_gen, W_val, W_out,
                                                  wb, bias, WgvT, WoT, wbbT, Vt);

    // stage 1 (fused): [G | V] = qf @ [W_gen | W_val] + [b_gen | b_val]
    k_gemm256<0><<<dim3(800), dim3(512), 0, stream>>>(qf_bf, WgvT, b_gen, b_val,
                                                      G_bf, Vt, 512, 10);

    // stage 2: fused attention
    k_attn<<<dim3(2560), dim3(512), 0, stream>>>(qf_bf, G_bf, Vt, wbbT, O_bf);

    // stage 3: out = O @ W_out + b_out + qf
    k_gemm256<2><<<dim3(160), dim3(512), 0, stream>>>(O_bf, WoT, b_out, qf,
                                                      out, nullptr, 2048, 2);
}

// Round 20
// 264.790 us; speedup vs baseline: 1.0312x; 1.0312x over previous
//
#include <hip/hip_runtime.h>
#include <hip/hip_bf16.h>

typedef __attribute__((ext_vector_type(4))) float f32x4;
typedef __attribute__((ext_vector_type(8))) short s16x8;
typedef __attribute__((ext_vector_type(4))) short s16x4;
typedef __attribute__((ext_vector_type(4))) unsigned int u32x4;

#define MFMA16(A, B, C) __builtin_amdgcn_mfma_f32_16x16x32_bf16((A), (B), (C), 0, 0, 0)

#define GLDS16(gsrc, ldst) __builtin_amdgcn_global_load_lds(                   \
    (const __attribute__((address_space(1))) void*)(gsrc),                    \
    (__attribute__((address_space(3))) void*)(ldst), 16, 0, 0)

__device__ __forceinline__ ushort f2bf(float f) {
    __hip_bfloat16 h = __float2bfloat16(f);
    return *reinterpret_cast<ushort*>(&h);
}

// p = exp(gelu_tanh(x)) : e2 = 2^(x*(c1*x^2+c0)) = e^{-2y}; g = x/(1+e2); p = e^g.
__device__ __forceinline__ float exp_gelu(float x) {
    float u = x * x;
    float m = fmaf(-0.1029439065f, u, -2.3022154392f);
    float e2 = __builtin_amdgcn_exp2f(x * m);
    float g = x * __builtin_amdgcn_rcpf(1.0f + e2);
    return __expf(g);
}

// ---------------- fused stage-0 prep ----------------
// [0,9600) cvt | [9600,11904) weight transposes | [11904,12704) wbbT | rest pad9
// wbbT layout: [h][k>>2][q][k&3] packed {bf16 wb, bf16 bias} u32.
__global__ __launch_bounds__(256) void k_prep(const float* __restrict__ qf,
                                              ushort* __restrict__ qf_bf,
                                              const float* __restrict__ W_gen,
                                              const float* __restrict__ W_val,
                                              const float* __restrict__ W_out,
                                              const float* __restrict__ wb,
                                              const float* __restrict__ bias,
                                              ushort* __restrict__ WgvT,
                                              ushort* __restrict__ WoT,
                                              unsigned int* __restrict__ wbbT,
                                              ushort* __restrict__ Vt) {
    __shared__ float tile[32][33];
    __shared__ float tb[32][33];
    int blk = blockIdx.x;
    int tx = threadIdx.x & 31, ty = threadIdx.x >> 5;   // 32 x 8
    if (blk < 9600) {                       // qf f32 -> bf16
        int i = (blk * 256 + threadIdx.x) * 4;
        float4 v = *(const float4*)(qf + i);
        ushort4 o;
        o.x = f2bf(v.x); o.y = f2bf(v.y); o.z = f2bf(v.z); o.w = f2bf(v.w);
        *(ushort4*)(qf_bf + i) = o;
        return;
    }
    blk -= 9600;
    if (blk < 2304) {                       // weight transposes
        const float* w; ushort* wt; int K, N, kx, ny;
        if (blk < 256)       { w = W_gen; wt = WgvT;             K = 512;  N = 512;
                               kx = blk & 15;          ny = blk >> 4; }
        else if (blk < 1280) { w = W_val; wt = WgvT + 512 * 512; K = 512;  N = 2048;
                               int b2 = blk - 256;  kx = b2 & 15; ny = b2 >> 4; }
        else                 { w = W_out; wt = WoT;              K = 2048; N = 512;
                               int b2 = blk - 1280; kx = b2 & 63; ny = b2 >> 6; }
        int k0 = kx * 32, n0 = ny * 32;
        #pragma unroll
        for (int i = ty; i < 32; i += 8)
            tile[i][tx] = w[(size_t)(k0 + i) * N + n0 + tx];
        __syncthreads();
        #pragma unroll
        for (int i = ty; i < 32; i += 8)
            wt[(size_t)(n0 + i) * K + k0 + tx] = f2bf(tile[tx][i]);
        return;
    }
    blk -= 2304;
    if (blk < 800) {                        // wbbT[h][k>>2][q][k&3]
        int h = blk / 100, rem = blk - h * 100;
        int kx = rem / 10, qx = rem - kx * 10;
        int k0 = kx * 32, q0 = qx * 32;
        #pragma unroll
        for (int i = ty; i < 32; i += 8)
            if (q0 + i < 300 && k0 + tx < 300) {
                size_t si = ((size_t)h * 300 + q0 + i) * 300 + k0 + tx;
                tile[i][tx] = wb[si];
                tb[i][tx]   = bias[si];
            }
        __syncthreads();
        #pragma unroll
        for (int i = ty; i < 32; i += 8)
            if (k0 + i < 300 && q0 + tx < 300) {
                int k = k0 + i;
                unsigned int pk = (unsigned int)f2bf(tile[tx][i])
                                | ((unsigned int)f2bf(tb[tx][i]) << 16);
                wbbT[(((size_t)h * 75 + (k >> 2)) * 300 + (q0 + tx)) * 4 + (k & 3)] = pk;
            }
        return;
    }
    blk -= 800;                             // zero chunk-9 pad (keys 300..303)
    int tid = blk * 256 + threadIdx.x;      // < 131072
    int bh = tid >> 8, v = tid & 255;
    *(s16x4*)(Vt + (size_t)bh * 77824 + 73728 + v * 16 + 12) = (s16x4){0, 0, 0, 0};
}

// ---------------- 256x256 GEMM (r11-validated structure) ----------------
// Vt layout: per (b*8+h): chunks 0..8 [256v][32k] + chunk9 [256v][16k].
template <int OUT>
__global__ __launch_bounds__(512, 2) void k_gemm256(const ushort* __restrict__ A,
                                                    const ushort* __restrict__ BT,
                                                    const float* __restrict__ b1,
                                                    const float* __restrict__ b2,
                                                    void* __restrict__ o1,
                                                    void* __restrict__ o2,
                                                    int K, int GY) {
    __shared__ __align__(16) ushort As[2][256 * 64];   // 2 x 32 KiB
    __shared__ __align__(16) ushort Bs[2][256 * 64];   // 2 x 32 KiB
    int id = blockIdx.x;
    int xcd = id & 7, s = id >> 3;
    int mxl = s / GY, ny = s - mxl * GY;
    int mx = xcd * 10 + mxl;
    if (mx >= 75) return;
    int m0 = mx * 256, n0g = ny * 256;

    int t = threadIdx.x, l = t & 63, w = t >> 6;
    int wr = w >> 2, wc = w & 3;            // 2 x 4 wave grid
    int lr = l & 15, lg = l >> 4;

    int rsrc[4], ksrc[4];
    #pragma unroll
    for (int c8 = 0; c8 < 4; ++c8) {
        int o = (c8 * 512 + t) * 16;
        int op = o ^ (((o >> 7) & 7) << 4);
        rsrc[c8] = op >> 7;                 // 0..255
        ksrc[c8] = (op & 127) >> 1;         // 0..63 (multiple of 8)
    }

    auto stage = [&](int kt, int buf) {
        int k0 = kt * 64;
        ushort* AsB = &As[buf][0];
        ushort* BsB = &Bs[buf][0];
        #pragma unroll
        for (int c8 = 0; c8 < 4; ++c8) {
            int dst = (c8 * 512 + w * 64) * 8;      // wave-uniform, ushorts
            GLDS16(A  + (size_t)(m0 + rsrc[c8]) * K + k0 + ksrc[c8], AsB + dst);
            GLDS16(BT + (size_t)(n0g + rsrc[c8]) * K + k0 + ksrc[c8], BsB + dst);
        }
    };

    f32x4 acc[8][4];
    #pragma unroll
    for (int i = 0; i < 8; ++i)
        #pragma unroll
        for (int j = 0; j < 4; ++j)
            acc[i][j] = (f32x4){0.f, 0.f, 0.f, 0.f};

    int NT = K >> 6;
    stage(0, 0);
    stage(1, 1);

    for (int kt = 0; kt < NT; ++kt) {
        if (kt + 1 < NT) asm volatile("s_waitcnt vmcnt(8)" ::: "memory");
        else             asm volatile("s_waitcnt vmcnt(0)" ::: "memory");
        __builtin_amdgcn_s_barrier();       // tile kt fully in LDS (all waves)

        int cur = kt & 1;
        const char* Ab = (const char*)&As[cur][0];
        const char* Bb = (const char*)&Bs[cur][0];
        #pragma unroll
        for (int ks = 0; ks < 2; ++ks) {
            int kb = (ks * 64 + lg * 16) ^ ((lr & 7) << 4);
            s16x8 af[8], bfv[4];
            #pragma unroll
            for (int rt = 0; rt < 8; ++rt)
                af[rt] = *(const s16x8*)(Ab + (wr * 128 + rt * 16 + lr) * 128 + kb);
            #pragma unroll
            for (int ct = 0; ct < 4; ++ct)
                bfv[ct] = *(const s16x8*)(Bb + (wc * 64 + ct * 16 + lr) * 128 + kb);
            #pragma unroll
            for (int rt = 0; rt < 8; ++rt)
                #pragma unroll
                for (int ct = 0; ct < 4; ++ct)
                    acc[rt][ct] = MFMA16(af[rt], bfv[ct], acc[rt][ct]);
        }

        __builtin_amdgcn_s_barrier();       // all waves done reading buf cur
        if (kt + 2 < NT) stage(kt + 2, cur);
    }

    if (OUT == 0) {
        if (n0g < 512) {
            ushort* G = (ushort*)o1;
            #pragma unroll
            for (int rt = 0; rt < 8; ++rt)
                #pragma unroll
                for (int ct = 0; ct < 4; ++ct) {
                    int col = n0g + wc * 64 + ct * 16 + lr;
                    float bv = b1[col];
                    #pragma unroll
                    for (int rr = 0; rr < 4; ++rr) {
                        int row = m0 + wr * 128 + rt * 16 + lg * 4 + rr;
                        G[(size_t)row * 512 + col] = f2bf(acc[rt][ct][rr] + bv);
                    }
                }
        } else {
            ushort* Vt = (ushort*)o2;
            #pragma unroll
            for (int rt = 0; rt < 8; ++rt) {
                int rl0 = m0 + wr * 128 + rt * 16 + lg * 4;   // %4 == 0
                int bb = rl0 / 300, key0 = rl0 - bb * 300;    // key0 %4 == 0
                #pragma unroll
                for (int ct = 0; ct < 4; ++ct) {
                    int colv = n0g - 512 + wc * 64 + ct * 16 + lr;
                    float bv = b2[colv];
                    int hh = colv >> 8, v = colv & 255;
                    s16x4 pw;
                    #pragma unroll
                    for (int rr = 0; rr < 4; ++rr)
                        pw[rr] = (short)f2bf(acc[rt][ct][rr] + bv);
                    size_t bhb = (size_t)(bb * 8 + hh) * 77824;
                    size_t addr = (key0 < 288)
                        ? bhb + (size_t)(key0 >> 5) * 8192 + v * 32 + (key0 & 31)
                        : bhb + 73728 + v * 16 + (key0 - 288);
                    *(s16x4*)(Vt + addr) = pw;
                }
            }
        }
    } else {
        float* out = (float*)o1;
        #pragma unroll
        for (int rt = 0; rt < 8; ++rt)
            #pragma unroll
            for (int ct = 0; ct < 4; ++ct) {
                int col = n0g + wc * 64 + ct * 16 + lr;
                float bv = b1[col];
                #pragma unroll
                for (int rr = 0; rr < 4; ++rr) {
                    int row = m0 + wr * 128 + rt * 16 + lg * 4 + rr;
                    size_t idx = (size_t)row * 512 + col;
                    out[idx] = acc[rt][ct][rr] + bv + b2[idx];
                }
            }
    }
}

// ---------------- fused attention: 512 threads (8 waves) ----------------
// Scores: 2-deep software pipeline (G + wbb for kt+1 issued before computing
// kt). PV: kc=0 V prefetched BEFORE the barrier (drained by its vmcnt(0));
// kc+1 V prefetched under kc's MFMAs; setprio(1) around MFMA clusters (T5).
__global__ __launch_bounds__(512, 6) void k_attn(const ushort* __restrict__ qf_bf,
                                                 const ushort* __restrict__ G_bf,
                                                 const ushort* __restrict__ Vt,
                                                 const unsigned int* __restrict__ wbb,
                                                 ushort* __restrict__ O) {
    __shared__ __align__(16) ushort P[64 * 320];   // 40,960 B swizzled
    __shared__ float partial[2][64];
    int id = blockIdx.x;
    int xcd = id & 7, s = id >> 3;        // s in [0,320)
    int h = s / 40; int r2 = s - h * 40;
    int bi = r2 / 5, qt = r2 - bi * 5;
    int b = xcd * 8 + bi;

    int t = threadIdx.x, l = t & 63, w = t >> 6;
    int lr = l & 15, lg = l >> 4;
    int wq = w & 3, wk = w >> 2;

    auto p_addr = [&](int q, int k) -> ushort* {
        int byte = (q * 640 + k * 2) ^ ((q & 15) << 4);
        return (ushort*)((char*)P + byte);
    };

    // Q fragment (B operand): col = q = lane&15
    int qr = min(qt * 64 + wq * 16 + lr, 299);
    const ushort* qp = qf_bf + ((size_t)(b * 300 + qr)) * 512 + h * 64 + lg * 8;
    s16x8 q0 = *(const s16x8*)(qp);
    s16x8 q1 = *(const s16x8*)(qp + 32);

    const unsigned int* wbbq = wbb + (size_t)h * 90000 + qr * 4;

    // ---- scores^T: 2-deep pipelined over this wave's key-half ----
    int qq = wq * 16 + lr;
    float ssum = 0.f;
    int ktlo = wk * 10, kthi = min(ktlo + 10, 18);
    const unsigned int* wp = wbbq + (size_t)(ktlo * 4 + lg) * 1200;
    const ushort* gp = G_bf + ((size_t)(b * 300) + ktlo * 16 + lr) * 512 + h * 64 + lg * 8;

    s16x8 g0 = *(const s16x8*)(gp);
    s16x8 g1 = *(const s16x8*)(gp + 32);
    u32x4 uv = *(const u32x4*)(wp);

    for (int kt = ktlo; kt < kthi - 1; ++kt) {
        const ushort* gpn = gp + 16 * 512;
        const unsigned int* wpn = wp + 4800;
        s16x8 ng0 = *(const s16x8*)(gpn);          // next-iter loads in flight
        s16x8 ng1 = *(const s16x8*)(gpn + 32);
        u32x4 nuv = *(const u32x4*)(wpn);

        f32x4 a = (f32x4){0.f, 0.f, 0.f, 0.f};
        a = MFMA16(g0, q0, a);
        a = MFMA16(g1, q1, a);
        int kbase = kt * 16 + lg * 4;
        s16x4 pw;
        #pragma unroll
        for (int r = 0; r < 4; ++r) {
            unsigned int u = uv[r];
            float wv = __builtin_bit_cast(float, u << 16);
            float bv = __builtin_bit_cast(float, u & 0xffff0000u);
            float x = fmaf(a[r], wv, bv);
            float p = exp_gelu(x);
            ssum += p;
            pw[r] = (short)f2bf(p);
        }
        *(s16x4*)p_addr(qq, kbase) = pw;
        g0 = ng0; g1 = ng1; uv = nuv; gp = gpn; wp = wpn;
    }
    {   // final main iteration kt = kthi-1
        f32x4 a = (f32x4){0.f, 0.f, 0.f, 0.f};
        a = MFMA16(g0, q0, a);
        a = MFMA16(g1, q1, a);
        int kbase = (kthi - 1) * 16 + lg * 4;
        s16x4 pw;
        #pragma unroll
        for (int r = 0; r < 4; ++r) {
            unsigned int u = uv[r];
            float wv = __builtin_bit_cast(float, u << 16);
            float bv = __builtin_bit_cast(float, u & 0xffff0000u);
            float x = fmaf(a[r], wv, bv);
            float p = exp_gelu(x);
            ssum += p;
            pw[r] = (short)f2bf(p);
        }
        *(s16x4*)p_addr(qq, kbase) = pw;
    }
    if (wk == 1) {                                  // peeled kt = 18
        int kcl = min(288 + lr, 299);
        const ushort* gpe = G_bf + ((size_t)(b * 300 + kcl)) * 512 + h * 64 + lg * 8;
        s16x8 e0 = *(const s16x8*)(gpe);
        s16x8 e1 = *(const s16x8*)(gpe + 32);
        f32x4 a = (f32x4){0.f, 0.f, 0.f, 0.f};
        a = MFMA16(e0, q0, a);
        a = MFMA16(e1, q1, a);
        int kbase = 288 + lg * 4;
        int g4 = min(72 + lg, 74);                  // lg=3 clamped (masked)
        u32x4 ev = *(const u32x4*)(wbbq + (size_t)g4 * 1200);
        s16x4 pw;
        #pragma unroll
        for (int r = 0; r < 4; ++r) {
            unsigned int u = ev[r];
            float wv = __builtin_bit_cast(float, u << 16);
            float bv = __builtin_bit_cast(float, u & 0xffff0000u);
            float x = fmaf(a[r], wv, bv);
            float p = (lg < 3) ? exp_gelu(x) : 0.f;
            ssum += p;
            pw[r] = (short)f2bf(p);
        }
        *(s16x4*)p_addr(qq, kbase) = pw;
    }

    // prefetch PV kc=0 V (drained by the barrier's vmcnt(0) -> ready after)
    size_t bhb = (size_t)(b * 8 + h) * 77824;
    const ushort* vbase = Vt + bhb + (size_t)(w * 32) * 32 + lg * 8;
    s16x8 vb0 = *(const s16x8*)(vbase + lr * 32);
    s16x8 vb1 = *(const s16x8*)(vbase + (16 + lr) * 32);

    // per-wave partial denominator for row qq (sum over lg groups)
    ssum += __shfl_xor(ssum, 16);
    ssum += __shfl_xor(ssum, 32);
    if (lg == 0) partial[wk][qq] = ssum;

    __syncthreads();   // the ONLY barrier: P + partial visible, vb0/vb1 landed

    // ---- PV: wave w owns v in [w*32, w*32+32) for all 64 q ----
    f32x4 acc[4][2];   // [qg][nt]
    #pragma unroll
    for (int qg = 0; qg < 4; ++qg)
        #pragma unroll
        for (int nt = 0; nt < 2; ++nt)
            acc[qg][nt] = (f32x4){0.f, 0.f, 0.f, 0.f};

    #pragma unroll
    for (int kc = 0; kc < 9; ++kc) {
        s16x8 nvb0, nvb1;
        if (kc < 8) {      // prefetch next chunk under this chunk's MFMAs
            nvb0 = *(const s16x8*)(vbase + (size_t)(kc + 1) * 8192 + lr * 32);
            nvb1 = *(const s16x8*)(vbase + (size_t)(kc + 1) * 8192 + (16 + lr) * 32);
        }
        __builtin_amdgcn_s_setprio(1);
        #pragma unroll
        for (int qg = 0; qg < 4; ++qg) {
            s16x8 pa = *(const s16x8*)p_addr(qg * 16 + lr, kc * 32 + lg * 8);
            acc[qg][0] = MFMA16(pa, vb0, acc[qg][0]);
            acc[qg][1] = MFMA16(pa, vb1, acc[qg][1]);
        }
        __builtin_amdgcn_s_setprio(0);
        if (kc < 8) { vb0 = nvb0; vb1 = nvb1; }
    }
    {   // chunk 9: keys 288..303 (16-wide); lanes lg>=2 contribute zeros
        const ushort* c9 = Vt + bhb + 73728 + (size_t)(w * 32) * 16 + lg * 8;
        s16x8 cb0, cb1;
        if (lg < 2) {
            cb0 = *(const s16x8*)(c9 + lr * 16);
            cb1 = *(const s16x8*)(c9 + (16 + lr) * 16);
        } else {
            cb0 = (s16x8){0,0,0,0,0,0,0,0};
            cb1 = (s16x8){0,0,0,0,0,0,0,0};
        }
        #pragma unroll
        for (int qg = 0; qg < 4; ++qg) {
            s16x8 pa = (lg < 2)
                ? *(const s16x8*)p_addr(qg * 16 + lr, 288 + lg * 8)
                : (s16x8){0,0,0,0,0,0,0,0};
            acc[qg][0] = MFMA16(pa, cb0, acc[qg][0]);
            acc[qg][1] = MFMA16(pa, cb1, acc[qg][1]);
        }
    }

    // ---- normalize + store ----
    #pragma unroll
    for (int qg = 0; qg < 4; ++qg)
        #pragma unroll
        for (int r = 0; r < 4; ++r) {
            int qloc = qg * 16 + lg * 4 + r;
            int q = qt * 64 + qloc;
            if (q < 300) {
                float iv = 1.0f / (partial[0][qloc] + partial[1][qloc]);
                #pragma unroll
                for (int nt = 0; nt < 2; ++nt) {
                    int v = w * 32 + nt * 16 + lr;
                    O[((size_t)(b * 300 + q)) * 2048 + h * 256 + v] =
                        f2bf(acc[qg][nt][r] * iv);
                }
            }
        }
}

extern "C" void kernel_launch(void* const* d_in, const int* in_sizes, int n_in,
                              void* d_out, int out_size, void* d_ws, size_t ws_size,
                              hipStream_t stream) {
    const float* qf    = (const float*)d_in[0];
    const float* bias  = (const float*)d_in[1];
    const float* W_gen = (const float*)d_in[2];
    const float* b_gen = (const float*)d_in[3];
    const float* W_val = (const float*)d_in[4];
    const float* b_val = (const float*)d_in[5];
    const float* W_out = (const float*)d_in[6];
    const float* b_out = (const float*)d_in[7];
    const float* wb    = (const float*)d_in[8];
    float* out = (float*)d_out;

    char* ws = (char*)d_ws;
    ushort* qf_bf = (ushort*)(ws);                       // 19,660,800 B
    ushort* G_bf  = (ushort*)(ws + 19660800);            // 19,660,800 B
    ushort* Vt    = (ushort*)(ws + 39321600);            // 79,691,776 B (tiled)
    ushort* O_bf  = (ushort*)(ws + 119013376);           // 78,643,200 B
    ushort* WgvT  = (ushort*)(ws + 197656576);           //  2,621,440 B
    ushort* WoT   = (ushort*)(ws + 200278016);           //  2,097,152 B
    unsigned int* wbbT = (unsigned int*)(ws + 202375168);//  2,880,000 B -> 205,255,168

    // stage 0 (fused): cvt + transposes + wbbT + chunk9 pad
    k_prep<<<dim3(13216), dim3(256), 0, stream>>>(qf, qf_bf, W_gen, W_val, W_out,
                                                  wb, bias, WgvT, WoT, wbbT, Vt);

    // stage 1 (fused): [G | V] = qf @ [W_gen | W_val] + [b_gen | b_val]
    k_gemm256<0><<<dim3(800), dim3(512), 0, stream>>>(qf_bf, WgvT, b_gen, b_val,
                                                      G_bf, Vt, 512, 10);

    // stage 2: fused attention
    k_attn<<<dim3(2560), dim3(512), 0, stream>>>(qf_bf, G_bf, Vt, wbbT, O_bf);

    // stage 3: out = O @ W_out + b_out + qf
    k_gemm256<2><<<dim3(160), dim3(512), 0, stream>>>(O_bf, WoT, b_out, qf,
                                                      out, nullptr, 2048, 2);
}